// Round 19
// baseline (102.185 us; speedup 1.0000x reference)
//
#include <hip/hip_runtime.h>
#include <hip/hip_bf16.h>

#define B_ 8
#define T_ 4096
#define C_ 256
#define H_ 256
#define K_ 3
#define NC 128          // time chunks (32 t each)
#define TC 32
#define WFRAG_ELEMS (24 * 32 * 64 * 8)   // [ks][ntg][lane][j] bf16

typedef __attribute__((ext_vector_type(8))) __bf16 bf16x8;
typedef __attribute__((ext_vector_type(4))) float f32x4;

__device__ __forceinline__ float sigm(float x) { return 1.0f / (1.0f + __expf(-x)); }

__device__ __forceinline__ ushort f2bf(float f) {
    union { float f; unsigned u; } v; v.f = f;
    return (ushort)((v.u + 0x7FFFu + ((v.u >> 16) & 1u)) >> 16);
}
__device__ __forceinline__ float bf2f(ushort u) {
    union { unsigned u; float f; } v; v.u = ((unsigned)u) << 16; return v.f;
}
__device__ __forceinline__ unsigned cvt_pk_bf16(float lo, float hi) {
    unsigned r;
    asm("v_cvt_pk_bf16_f32 %0, %1, %2" : "=v"(r) : "v"(lo), "v"(hi));
    return r;
}

// Gather f_w,z_w into B-fragment-linear bf16 layout for mfma_f32_16x16x32_bf16.
__global__ __launch_bounds__(256) void wfrag_kernel(const float* __restrict__ fw,
                                                    const float* __restrict__ zw,
                                                    ushort* __restrict__ wfrag) {
    int idx = blockIdx.x * 256 + threadIdx.x;
    if (idx >= WFRAG_ELEMS) return;
    int j   = idx & 7;
    int l   = (idx >> 3) & 63;
    int ntg = (idx >> 9) & 31;
    int ks  = idx >> 14;
    int n = ntg * 16 + (l & 15);
    int kappa = ks * 32 + (l >> 4) * 8 + j;
    int k = kappa >> 8, c = kappa & 255;
    const float* w = (n < 256) ? fw : zw;
    int h = n & 255;
    wfrag[idx] = f2bf(w[(h * C_ + c) * K_ + k]);
}

__device__ __forceinline__ void bload(const ushort* wb, int ks, const int (&ntg)[4],
                                      bf16x8 (&dst)[4]) {
#pragma unroll
    for (int ni = 0; ni < 4; ++ni)
        dst[ni] = *(const bf16x8*)(wb + (size_t)ks * 16384 + (size_t)ntg[ni] * 512);
}

__device__ __forceinline__ void conv_step(const char* smem, int ks, int lr, int lg,
                                          const bf16x8 (&bfr)[4], f32x4 (&acc)[4][4]) {
    const int k = ks >> 3;
    const int cb = ((ks & 7) * 32 + lg * 8) * 2;
    bf16x8 afr[4];
#pragma unroll
    for (int mi = 0; mi < 4; ++mi) {
        int row = mi * 16 + lr + k;
        afr[mi] = *(const bf16x8*)(smem + row * 512 + (cb ^ ((row & 7) << 4)));
    }
    __builtin_amdgcn_s_setprio(1);
#pragma unroll
    for (int ni = 0; ni < 4; ++ni)
#pragma unroll
        for (int mi = 0; mi < 4; ++mi)
            acc[mi][ni] = __builtin_amdgcn_mfma_f32_16x16x32_bf16(afr[mi], bfr[ni], acc[mi][ni], 0, 0, 0);
    __builtin_amdgcn_s_setprio(0);
}

// ---------------------------------------------------------------------------
// Fused conv (f and z) + gates + per-chunk affine scan (R14/R18 structure)
// with DEPTH-4 B prefetch: bload(ks+3) issued before conv_step(ks), so ~3
// MFMA clusters (~300 cyc) cover the ~200+ cyc L2 latency of each B set.
// ---------------------------------------------------------------------------
__global__ __launch_bounds__(512, 4) void conv_scan_kernel(const float* __restrict__ x,
                                                           const ushort* __restrict__ wfrag,
                                                           const float* __restrict__ fb,
                                                           const float* __restrict__ zb,
                                                           unsigned* __restrict__ AP,
                                                           float2* __restrict__ ab) {
    __shared__ __align__(16) char smem[65536];   // union: xs 66x512B | buf 64x256 uint
    unsigned* buf = (unsigned*)smem;

    const int b = blockIdx.y;
    const int t0 = blockIdx.x * 64;
    const int tid = threadIdx.x;

    // Stage x[b, t0-1 .. t0+64, :] as bf16, swizzled: byte = row*512 + ((2c) ^ ((row&7)<<4))
    if (blockIdx.x == 0 || blockIdx.x == gridDim.x - 1) {
        for (int idx = tid; idx < 66 * 64; idx += 512) {
            int row = idx >> 6;
            int c4 = (idx & 63) * 4;
            int t = t0 - 1 + row;
            float4 v = make_float4(0.f, 0.f, 0.f, 0.f);
            if (t >= 0 && t < T_) v = *(const float4*)(x + ((size_t)(b * T_ + t)) * C_ + c4);
            uint2 w2 = make_uint2(cvt_pk_bf16(v.x, v.y), cvt_pk_bf16(v.z, v.w));
            *(uint2*)(smem + row * 512 + ((c4 * 2) ^ ((row & 7) << 4))) = w2;
        }
    } else {
        for (int idx = tid; idx < 66 * 64; idx += 512) {
            int row = idx >> 6;
            int c4 = (idx & 63) * 4;
            int t = t0 - 1 + row;
            float4 v = *(const float4*)(x + ((size_t)(b * T_ + t)) * C_ + c4);
            uint2 w2 = make_uint2(cvt_pk_bf16(v.x, v.y), cvt_pk_bf16(v.z, v.w));
            *(uint2*)(smem + row * 512 + ((c4 * 2) ^ ((row & 7) << 4))) = w2;
        }
    }
    __syncthreads();

    const int wv = tid >> 6;
    const int l  = tid & 63;
    const int lr = l & 15;
    const int lg = l >> 4;
    const int h0 = wv * 32;

    f32x4 acc[4][4];
#pragma unroll
    for (int ni = 0; ni < 4; ++ni) {
        float bv = (ni < 2 ? fb : zb)[h0 + (ni & 1) * 16 + lr];
        f32x4 bvv = {bv, bv, bv, bv};
#pragma unroll
        for (int mi = 0; mi < 4; ++mi) acc[mi][ni] = bvv;
    }

    const ushort* wb = wfrag + (size_t)l * 8;
    int ntg_[4];
#pragma unroll
    for (int ni = 0; ni < 4; ++ni)
        ntg_[ni] = (ni < 2) ? (wv * 2 + ni) : (16 + wv * 2 + ni - 2);

    // Depth-4 rotating B prefetch (T4 counted-vmcnt pattern, compiler-friendly).
    bf16x8 b0[4], b1[4], b2[4], b3[4];
    bload(wb, 0, ntg_, b0);
    bload(wb, 1, ntg_, b1);
    bload(wb, 2, ntg_, b2);
#pragma unroll 1
    for (int ks = 0; ks < 24; ks += 4) {
        bload(wb, ks + 3, ntg_, b3);
        conv_step(smem, ks, lr, lg, b0, acc);
        if (ks + 4 < 24) bload(wb, ks + 4, ntg_, b0);
        conv_step(smem, ks + 1, lr, lg, b1, acc);
        if (ks + 5 < 24) bload(wb, ks + 5, ntg_, b1);
        conv_step(smem, ks + 2, lr, lg, b2, acc);
        if (ks + 6 < 24) bload(wb, ks + 6, ntg_, b2);
        conv_step(smem, ks + 3, lr, lg, b3, acc);
    }

    // One-phase epilogue: sigmoid + pack {a,f} for both chunks into buf[64][256].
    __syncthreads();                       // xs dead; buf aliases it
#pragma unroll
    for (int mi = 0; mi < 4; ++mi) {
#pragma unroll
        for (int ni = 0; ni < 2; ++ni) {
            const int h = h0 + ni * 16 + lr;
#pragma unroll
            for (int r = 0; r < 4; ++r) {
                float fv = sigm(acc[mi][ni][r]);
                float av = sigm(acc[mi][ni + 2][r]) * (1.0f - fv);
                int tl = (mi & 1) * 16 + lg * 4 + r;          // t within chunk
                int trow = (mi >> 1) * 32 + tl;               // buf row
                buf[trow * 256 + (h ^ ((tl << 2) & 31))] = cvt_pk_bf16(av, fv);
            }
        }
    }
    __syncthreads();

    // Parallel per-chunk scan: all 512 threads (ch = tid>>8, h = tid&255).
    {
        const int ch = tid >> 8;
        const int h = tid & 255;
        const int chunk = blockIdx.x * 2 + ch;
        const int r0 = chunk * TC;
        const unsigned* bp = buf + ch * 32 * 256;
        unsigned* app = AP + ((size_t)b * T_ + r0) * H_ + h;
        unsigned u = bp[h];
        float A = bf2f((ushort)(u & 0xffff));
        float Pp = 1.0f;
        float f_prev = bf2f((ushort)(u >> 16));
        app[0] = cvt_pk_bf16(A, Pp);
#pragma unroll 8
        for (int j = 1; j < TC; ++j) {
            u = bp[j * 256 + (h ^ ((j << 2) & 31))];
            float a = bf2f((ushort)(u & 0xffff));
            float f = bf2f((ushort)(u >> 16));
            A = fmaf(f_prev, A, a);
            Pp *= f_prev;
            f_prev = f;
            app[(size_t)j * H_] = cvt_pk_bf16(A, Pp);
        }
        // per-chunk map on seam-scaled state: u_{c+1} = a_c + b_c * u_c
        ab[((size_t)b * NC + chunk) * H_ + h] = make_float2(f_prev * A, f_prev * Pp);
    }
}

// ---------------------------------------------------------------------------
// Chain + apply, vectorized (R18-proven). Chunk perm: (c>>1)%8 == p%8.
// ---------------------------------------------------------------------------
__global__ __launch_bounds__(256) void chainapply_kernel(const unsigned* __restrict__ AP,
                                                         const float2* __restrict__ ab,
                                                         const float* __restrict__ init_f,
                                                         const float* __restrict__ init_z,
                                                         float* __restrict__ out) {
    __shared__ float us[256];
    const int p = blockIdx.x;
    const int tq = p >> 3;
    const int c = 16 * (tq >> 1) + 2 * (p & 7) + (tq & 1);   // bijective, (c>>1)%8==p%8
    const int b = blockIdx.y;
    const int tid = threadIdx.x;

    if (tid < 64) {
        const int h4 = tid * 4;
        float4 if4 = *(const float4*)(init_f + b * H_ + h4);
        float4 iz4 = *(const float4*)(init_z + b * H_ + h4);
        float u[4];
#pragma unroll
        for (int q = 0; q < 4; ++q) {
            float f0 = sigm(q == 0 ? if4.x : q == 1 ? if4.y : q == 2 ? if4.z : if4.w);
            float z0 = sigm(q == 0 ? iz4.x : q == 1 ? iz4.y : q == 2 ? iz4.z : iz4.w);
            float s0 = z0 * (1.0f - f0);
            if (c == 0) out[(size_t)b * (T_ + 1) * H_ + h4 + q] = s0;
            u[q] = f0 * s0;
        }
        const float* abp = (const float*)(ab + (size_t)b * NC * H_ + h4);
#pragma unroll 4
        for (int cc = 0; cc < c; ++cc) {
            float4 q01 = *(const float4*)(abp + (size_t)cc * (2 * H_));      // {a0,b0,a1,b1}
            float4 q23 = *(const float4*)(abp + (size_t)cc * (2 * H_) + 4);  // {a2,b2,a3,b3}
            u[0] = fmaf(q01.y, u[0], q01.x);
            u[1] = fmaf(q01.w, u[1], q01.z);
            u[2] = fmaf(q23.y, u[2], q23.x);
            u[3] = fmaf(q23.w, u[3], q23.z);
        }
#pragma unroll
        for (int q = 0; q < 4; ++q) us[h4 + q] = u[q];
    }
    __syncthreads();

    const int jr = tid >> 6;              // 0..3
    const int h4 = (tid & 63) * 4;
    const float4 s4 = *(const float4*)(us + h4);
    const unsigned* app = AP + ((size_t)b * T_ + c * TC) * H_ + h4;
    float* op = out + ((size_t)b * (T_ + 1) + c * TC + 1) * H_ + h4;
#pragma unroll
    for (int pj = 0; pj < 8; ++pj) {
        const int j = pj * 4 + jr;
        const uint4 u4 = *(const uint4*)(app + (size_t)j * H_);
        float4 o;
        o.x = fmaf(bf2f((ushort)(u4.x >> 16)), s4.x, bf2f((ushort)(u4.x & 0xffff)));
        o.y = fmaf(bf2f((ushort)(u4.y >> 16)), s4.y, bf2f((ushort)(u4.y & 0xffff)));
        o.z = fmaf(bf2f((ushort)(u4.z >> 16)), s4.z, bf2f((ushort)(u4.z & 0xffff)));
        o.w = fmaf(bf2f((ushort)(u4.w >> 16)), s4.w, bf2f((ushort)(u4.w & 0xffff)));
        *(float4*)(op + (size_t)j * H_) = o;
    }
}

extern "C" void kernel_launch(void* const* d_in, const int* in_sizes, int n_in,
                              void* d_out, int out_size, void* d_ws, size_t ws_size,
                              hipStream_t stream) {
    const float* inputs = (const float*)d_in[0];   // [B,T,C]
    const float* init_f = (const float*)d_in[1];   // [B,H]
    const float* init_z = (const float*)d_in[2];   // [B,H]
    const float* f_w    = (const float*)d_in[3];   // [H,C,K]
    const float* f_b    = (const float*)d_in[4];   // [H]
    const float* z_w    = (const float*)d_in[5];   // [H,C,K]
    const float* z_b    = (const float*)d_in[6];   // [H]
    float* out = (float*)d_out;                    // [B,T+1,H]

    // ws: wfrag 768KB | AP (B*T*H uint, 32MB) | ab (B*NC*H float2, 2MB)
    ushort* wfrag = (ushort*)d_ws;
    unsigned* AP  = (unsigned*)(wfrag + WFRAG_ELEMS);
    float2* ab    = (float2*)(AP + (size_t)B_ * T_ * H_);

    wfrag_kernel<<<(WFRAG_ELEMS + 255) / 256, 256, 0, stream>>>(f_w, z_w, wfrag);

    dim3 cgrid(T_ / 64, B_, 1);
    conv_scan_kernel<<<cgrid, 512, 0, stream>>>(inputs, wfrag, f_b, z_b, AP, ab);

    dim3 agrid(NC, B_, 1);
    chainapply_kernel<<<agrid, 256, 0, stream>>>(AP, ab, init_f, init_z, out);
}

// Round 20
// 62.009 us; speedup vs baseline: 1.6479x; 1.6479x over previous
//
#include <hip/hip_runtime.h>
#include <hip/hip_bf16.h>

#define B_ 8
#define T_ 4096
#define C_ 256
#define H_ 256
#define K_ 3
#define NC 128          // time chunks (32 t each)
#define TC 32
#define WFRAG_ELEMS (24 * 32 * 64 * 8)   // [ks][ntg][lane][j] bf16

typedef __attribute__((ext_vector_type(8))) __bf16 bf16x8;
typedef __attribute__((ext_vector_type(4))) float f32x4;

__device__ __forceinline__ float sigm(float x) { return 1.0f / (1.0f + __expf(-x)); }

__device__ __forceinline__ ushort f2bf(float f) {
    union { float f; unsigned u; } v; v.f = f;
    return (ushort)((v.u + 0x7FFFu + ((v.u >> 16) & 1u)) >> 16);
}
__device__ __forceinline__ float bf2f(ushort u) {
    union { unsigned u; float f; } v; v.u = ((unsigned)u) << 16; return v.f;
}
__device__ __forceinline__ unsigned cvt_pk_bf16(float lo, float hi) {
    unsigned r;
    asm("v_cvt_pk_bf16_f32 %0, %1, %2" : "=v"(r) : "v"(lo), "v"(hi));
    return r;
}

// Gather f_w,z_w into B-fragment-linear bf16 layout for mfma_f32_16x16x32_bf16.
__global__ __launch_bounds__(256) void wfrag_kernel(const float* __restrict__ fw,
                                                    const float* __restrict__ zw,
                                                    ushort* __restrict__ wfrag) {
    int idx = blockIdx.x * 256 + threadIdx.x;
    if (idx >= WFRAG_ELEMS) return;
    int j   = idx & 7;
    int l   = (idx >> 3) & 63;
    int ntg = (idx >> 9) & 31;
    int ks  = idx >> 14;
    int n = ntg * 16 + (l & 15);
    int kappa = ks * 32 + (l >> 4) * 8 + j;
    int k = kappa >> 8, c = kappa & 255;
    const float* w = (n < 256) ? fw : zw;
    int h = n & 255;
    wfrag[idx] = f2bf(w[(h * C_ + c) * K_ + k]);
}

__device__ __forceinline__ void bload(const ushort* wb, int ks, const int (&ntg)[4],
                                      bf16x8 (&dst)[4]) {
#pragma unroll
    for (int ni = 0; ni < 4; ++ni)
        dst[ni] = *(const bf16x8*)(wb + (size_t)ks * 16384 + (size_t)ntg[ni] * 512);
}

__device__ __forceinline__ void conv_step(const char* smem, int ks, int lr, int lg,
                                          const bf16x8 (&bfr)[4], f32x4 (&acc)[4][4]) {
    const int k = ks >> 3;
    const int cb = ((ks & 7) * 32 + lg * 8) * 2;
    bf16x8 afr[4];
#pragma unroll
    for (int mi = 0; mi < 4; ++mi) {
        int row = mi * 16 + lr + k;
        afr[mi] = *(const bf16x8*)(smem + row * 512 + (cb ^ ((row & 7) << 4)));
    }
    __builtin_amdgcn_s_setprio(1);
#pragma unroll
    for (int ni = 0; ni < 4; ++ni)
#pragma unroll
        for (int mi = 0; mi < 4; ++mi)
            acc[mi][ni] = __builtin_amdgcn_mfma_f32_16x16x32_bf16(afr[mi], bfr[ni], acc[mi][ni], 0, 0, 0);
    __builtin_amdgcn_s_setprio(0);
}

// ---------------------------------------------------------------------------
// Fused conv (f and z) + gates + per-chunk affine scan (R14/R18 structure,
// best measured: depth-2 ping-pong at the 124/128 register budget).
// Block: 64 t x 256 h, 8 waves. One-phase epilogue, 64KB LDS.
// ---------------------------------------------------------------------------
__global__ __launch_bounds__(512, 4) void conv_scan_kernel(const float* __restrict__ x,
                                                           const ushort* __restrict__ wfrag,
                                                           const float* __restrict__ fb,
                                                           const float* __restrict__ zb,
                                                           unsigned* __restrict__ AP,
                                                           float2* __restrict__ ab) {
    __shared__ __align__(16) char smem[65536];   // union: xs 66x512B | buf 64x256 uint
    unsigned* buf = (unsigned*)smem;

    const int b = blockIdx.y;
    const int t0 = blockIdx.x * 64;
    const int tid = threadIdx.x;

    // Stage x[b, t0-1 .. t0+64, :] as bf16, swizzled: byte = row*512 + ((2c) ^ ((row&7)<<4))
    if (blockIdx.x == 0 || blockIdx.x == gridDim.x - 1) {
        for (int idx = tid; idx < 66 * 64; idx += 512) {
            int row = idx >> 6;
            int c4 = (idx & 63) * 4;
            int t = t0 - 1 + row;
            float4 v = make_float4(0.f, 0.f, 0.f, 0.f);
            if (t >= 0 && t < T_) v = *(const float4*)(x + ((size_t)(b * T_ + t)) * C_ + c4);
            uint2 w2 = make_uint2(cvt_pk_bf16(v.x, v.y), cvt_pk_bf16(v.z, v.w));
            *(uint2*)(smem + row * 512 + ((c4 * 2) ^ ((row & 7) << 4))) = w2;
        }
    } else {
        for (int idx = tid; idx < 66 * 64; idx += 512) {
            int row = idx >> 6;
            int c4 = (idx & 63) * 4;
            int t = t0 - 1 + row;
            float4 v = *(const float4*)(x + ((size_t)(b * T_ + t)) * C_ + c4);
            uint2 w2 = make_uint2(cvt_pk_bf16(v.x, v.y), cvt_pk_bf16(v.z, v.w));
            *(uint2*)(smem + row * 512 + ((c4 * 2) ^ ((row & 7) << 4))) = w2;
        }
    }
    __syncthreads();

    const int wv = tid >> 6;
    const int l  = tid & 63;
    const int lr = l & 15;
    const int lg = l >> 4;
    const int h0 = wv * 32;

    f32x4 acc[4][4];
#pragma unroll
    for (int ni = 0; ni < 4; ++ni) {
        float bv = (ni < 2 ? fb : zb)[h0 + (ni & 1) * 16 + lr];
        f32x4 bvv = {bv, bv, bv, bv};
#pragma unroll
        for (int mi = 0; mi < 4; ++mi) acc[mi][ni] = bvv;
    }

    const ushort* wb = wfrag + (size_t)l * 8;
    int ntg_[4];
#pragma unroll
    for (int ni = 0; ni < 4; ++ni)
        ntg_[ni] = (ni < 2) ? (wv * 2 + ni) : (16 + wv * 2 + ni - 2);

    // Conv with depth-2 ping-pong B prefetch (proven schedule).
    bf16x8 ba[4], bb[4];
    bload(wb, 0, ntg_, ba);
#pragma unroll 1
    for (int ks = 0; ks < 24; ks += 2) {
        bload(wb, ks + 1, ntg_, bb);
        conv_step(smem, ks, lr, lg, ba, acc);
        if (ks + 2 < 24) bload(wb, ks + 2, ntg_, ba);
        conv_step(smem, ks + 1, lr, lg, bb, acc);
    }

    // One-phase epilogue: sigmoid + pack {a,f} for both chunks into buf[64][256].
    __syncthreads();                       // xs dead; buf aliases it
#pragma unroll
    for (int mi = 0; mi < 4; ++mi) {
#pragma unroll
        for (int ni = 0; ni < 2; ++ni) {
            const int h = h0 + ni * 16 + lr;
#pragma unroll
            for (int r = 0; r < 4; ++r) {
                float fv = sigm(acc[mi][ni][r]);
                float av = sigm(acc[mi][ni + 2][r]) * (1.0f - fv);
                int tl = (mi & 1) * 16 + lg * 4 + r;          // t within chunk
                int trow = (mi >> 1) * 32 + tl;               // buf row
                buf[trow * 256 + (h ^ ((tl << 2) & 31))] = cvt_pk_bf16(av, fv);
            }
        }
    }
    __syncthreads();

    // Parallel per-chunk scan: all 512 threads (ch = tid>>8, h = tid&255).
    {
        const int ch = tid >> 8;
        const int h = tid & 255;
        const int chunk = blockIdx.x * 2 + ch;
        const int r0 = chunk * TC;
        const unsigned* bp = buf + ch * 32 * 256;
        unsigned* app = AP + ((size_t)b * T_ + r0) * H_ + h;
        unsigned u = bp[h];
        float A = bf2f((ushort)(u & 0xffff));
        float Pp = 1.0f;
        float f_prev = bf2f((ushort)(u >> 16));
        app[0] = cvt_pk_bf16(A, Pp);
#pragma unroll 8
        for (int j = 1; j < TC; ++j) {
            u = bp[j * 256 + (h ^ ((j << 2) & 31))];
            float a = bf2f((ushort)(u & 0xffff));
            float f = bf2f((ushort)(u >> 16));
            A = fmaf(f_prev, A, a);
            Pp *= f_prev;
            f_prev = f;
            app[(size_t)j * H_] = cvt_pk_bf16(A, Pp);
        }
        // per-chunk map on seam-scaled state: u_{c+1} = a_c + b_c * u_c
        ab[((size_t)b * NC + chunk) * H_ + h] = make_float2(f_prev * A, f_prev * Pp);
    }
}

// ---------------------------------------------------------------------------
// Chain + apply, vectorized (R18-proven). Chunk perm: (c>>1)%8 == p%8.
// Phase 1: 64 threads chain 4 h each (float4 ab loads, 4 indep FMA chains),
// u to LDS. Phase 2: all 256 threads apply j-split, uint4/float4 (16B/lane).
// ---------------------------------------------------------------------------
__global__ __launch_bounds__(256) void chainapply_kernel(const unsigned* __restrict__ AP,
                                                         const float2* __restrict__ ab,
                                                         const float* __restrict__ init_f,
                                                         const float* __restrict__ init_z,
                                                         float* __restrict__ out) {
    __shared__ float us[256];
    const int p = blockIdx.x;
    const int tq = p >> 3;
    const int c = 16 * (tq >> 1) + 2 * (p & 7) + (tq & 1);   // bijective, (c>>1)%8==p%8
    const int b = blockIdx.y;
    const int tid = threadIdx.x;

    if (tid < 64) {
        const int h4 = tid * 4;
        float4 if4 = *(const float4*)(init_f + b * H_ + h4);
        float4 iz4 = *(const float4*)(init_z + b * H_ + h4);
        float u[4];
#pragma unroll
        for (int q = 0; q < 4; ++q) {
            float f0 = sigm(q == 0 ? if4.x : q == 1 ? if4.y : q == 2 ? if4.z : if4.w);
            float z0 = sigm(q == 0 ? iz4.x : q == 1 ? iz4.y : q == 2 ? iz4.z : iz4.w);
            float s0 = z0 * (1.0f - f0);
            if (c == 0) out[(size_t)b * (T_ + 1) * H_ + h4 + q] = s0;
            u[q] = f0 * s0;
        }
        const float* abp = (const float*)(ab + (size_t)b * NC * H_ + h4);
#pragma unroll 4
        for (int cc = 0; cc < c; ++cc) {
            float4 q01 = *(const float4*)(abp + (size_t)cc * (2 * H_));      // {a0,b0,a1,b1}
            float4 q23 = *(const float4*)(abp + (size_t)cc * (2 * H_) + 4);  // {a2,b2,a3,b3}
            u[0] = fmaf(q01.y, u[0], q01.x);
            u[1] = fmaf(q01.w, u[1], q01.z);
            u[2] = fmaf(q23.y, u[2], q23.x);
            u[3] = fmaf(q23.w, u[3], q23.z);
        }
#pragma unroll
        for (int q = 0; q < 4; ++q) us[h4 + q] = u[q];
    }
    __syncthreads();

    const int jr = tid >> 6;              // 0..3
    const int h4 = (tid & 63) * 4;
    const float4 s4 = *(const float4*)(us + h4);
    const unsigned* app = AP + ((size_t)b * T_ + c * TC) * H_ + h4;
    float* op = out + ((size_t)b * (T_ + 1) + c * TC + 1) * H_ + h4;
#pragma unroll
    for (int pj = 0; pj < 8; ++pj) {
        const int j = pj * 4 + jr;
        const uint4 u4 = *(const uint4*)(app + (size_t)j * H_);
        float4 o;
        o.x = fmaf(bf2f((ushort)(u4.x >> 16)), s4.x, bf2f((ushort)(u4.x & 0xffff)));
        o.y = fmaf(bf2f((ushort)(u4.y >> 16)), s4.y, bf2f((ushort)(u4.y & 0xffff)));
        o.z = fmaf(bf2f((ushort)(u4.z >> 16)), s4.z, bf2f((ushort)(u4.z & 0xffff)));
        o.w = fmaf(bf2f((ushort)(u4.w >> 16)), s4.w, bf2f((ushort)(u4.w & 0xffff)));
        *(float4*)(op + (size_t)j * H_) = o;
    }
}

extern "C" void kernel_launch(void* const* d_in, const int* in_sizes, int n_in,
                              void* d_out, int out_size, void* d_ws, size_t ws_size,
                              hipStream_t stream) {
    const float* inputs = (const float*)d_in[0];   // [B,T,C]
    const float* init_f = (const float*)d_in[1];   // [B,H]
    const float* init_z = (const float*)d_in[2];   // [B,H]
    const float* f_w    = (const float*)d_in[3];   // [H,C,K]
    const float* f_b    = (const float*)d_in[4];   // [H]
    const float* z_w    = (const float*)d_in[5];   // [H,C,K]
    const float* z_b    = (const float*)d_in[6];   // [H]
    float* out = (float*)d_out;                    // [B,T+1,H]

    // ws: wfrag 768KB | AP (B*T*H uint, 32MB) | ab (B*NC*H float2, 2MB)
    ushort* wfrag = (ushort*)d_ws;
    unsigned* AP  = (unsigned*)(wfrag + WFRAG_ELEMS);
    float2* ab    = (float2*)(AP + (size_t)B_ * T_ * H_);

    wfrag_kernel<<<(WFRAG_ELEMS + 255) / 256, 256, 0, stream>>>(f_w, z_w, wfrag);

    dim3 cgrid(T_ / 64, B_, 1);
    conv_scan_kernel<<<cgrid, 512, 0, stream>>>(inputs, wfrag, f_b, z_b, AP, ab);

    dim3 agrid(NC, B_, 1);
    chainapply_kernel<<<agrid, 256, 0, stream>>>(AP, ab, init_f, init_z, out);
}